// Round 7
// baseline (327.618 us; speedup 1.0000x reference)
//
#include <hip/hip_runtime.h>

// CREStereo grouped correlation, round 7.
// R6: main 62us but VGPR=172 -> 2 waves/SIMD (occ 9.9%), latency-bound with
// both pipes idle. R7:
//  - __launch_bounds__(256,3): 172 is just over the 512/3=170 cliff; shaving
//    <=4 VGPRs buys +50% resident waves.
//  - Left transpose ELIMINATED (right-only pre-pass, ~half the pre-pass time).
//    Left staged per-block in LDS from CHW f32: 16-px blocks, thread t reads
//    the full 64B line left[c=t][P0..P0+15] -> zero line re-fetch (fixes R4's
//    failure mode, which used 4-px blocks and re-fetched each line 4x).
// Wave layout unchanged from R6: 4 px x 16 lanes, lane owns 16 ch (2x half8).

namespace {
constexpr int kB = 2;
constexpr int kC = 256;
constexpr int kH = 96;
constexpr int kW = 192;
constexpr int kG = 4;
constexpr int kGC = kC / kG;              // 64
constexpr int kK = 9;
constexpr int kHW = kH * kW;              // 18432
constexpr size_t kPlane = (size_t)kC * kHW;
constexpr int kPxPerBlock = 16;           // 4 waves x 4 px
constexpr int kBlocksPerBatch = kHW / kPxPerBlock;  // 1152
}

typedef _Float16 half8_t __attribute__((ext_vector_type(8)));
typedef _Float16 half4_t __attribute__((ext_vector_type(4)));
typedef _Float16 half2_t __attribute__((ext_vector_type(2)));

__device__ __forceinline__ float dot8(half8_t a, half8_t b, float acc) {
#if __has_builtin(__builtin_amdgcn_fdot2)
  #pragma unroll
  for (int i = 0; i < 4; ++i) {
    half2_t a2 = {a[2 * i], a[2 * i + 1]};
    half2_t b2 = {b[2 * i], b[2 * i + 1]};
    acc = __builtin_amdgcn_fdot2(a2, b2, acc, false);
  }
#else
  #pragma unroll
  for (int i = 0; i < 8; ++i) acc += (float)a[i] * (float)b[i];
#endif
  return acc;
}

// ---- right-only transpose [C][HW] f32 -> [HW][C] fp16 ----
__global__ __launch_bounds__(256) void transpose_right_fp16(
    const float* __restrict__ right, _Float16* __restrict__ right_t)
{
  __shared__ float tile[64][65];
  int pt = blockIdx.x;          // pixel tile 0..287
  int ct = blockIdx.y;          // channel tile 0..3
  int b  = blockIdx.z;
  int p0 = pt * 64, c0 = ct * 64;
  const float* inb = right   + (size_t)b * kPlane;
  _Float16*   outb = right_t + (size_t)b * kPlane;
  int t = threadIdx.x;
  int cl = t >> 2;              // channel within tile
  int q  = t & 3;
  #pragma unroll
  for (int i = 0; i < 4; ++i) {
    int j = q + 4 * i;          // float4 index along pixels
    float4 v = *(const float4*)(inb + (size_t)(c0 + cl) * kHW + p0 + 4 * j);
    tile[cl][4 * j + 0] = v.x;
    tile[cl][4 * j + 1] = v.y;
    tile[cl][4 * j + 2] = v.z;
    tile[cl][4 * j + 3] = v.w;
  }
  __syncthreads();
  int pl = t >> 2;              // pixel within tile
  #pragma unroll
  for (int i = 0; i < 4; ++i) {
    int c4 = (t & 3) + 4 * i;   // half4 index along channels
    half4_t hv;
    hv[0] = (_Float16)tile[4 * c4 + 0][pl];
    hv[1] = (_Float16)tile[4 * c4 + 1][pl];
    hv[2] = (_Float16)tile[4 * c4 + 2][pl];
    hv[3] = (_Float16)tile[4 * c4 + 3][pl];
    *(half4_t*)(outb + (size_t)(p0 + pl) * kC + c0 + 4 * c4) = hv;
  }
}

// ---- main: block = 16 px; wave = 4 px x 16 lanes; lane owns 16 channels ----
__global__ __launch_bounds__(256, 3) void corr_fp16_kernel(
    const float* __restrict__ left, const _Float16* __restrict__ right_t,
    const float* __restrict__ flow, const float* __restrict__ extra,
    float* __restrict__ out)
{
  __shared__ _Float16 ldsL[kPxPerBlock][kC];   // 8 KB

  int gb = blockIdx.x;
  int b  = gb / kBlocksPerBatch;
  int P0 = (gb % kBlocksPerBatch) * kPxPerBlock;

  {  // stage left: thread t = channel t, reads its full 64B line (16 px)
    int t = threadIdx.x;
    const float* src = left + (size_t)b * kPlane + (size_t)t * kHW + P0;
    #pragma unroll
    for (int j = 0; j < 4; ++j) {
      float4 v = *(const float4*)(src + 4 * j);
      ldsL[4 * j + 0][t] = (_Float16)v.x;
      ldsL[4 * j + 1][t] = (_Float16)v.y;
      ldsL[4 * j + 2][t] = (_Float16)v.z;
      ldsL[4 * j + 3][t] = (_Float16)v.w;
    }
  }
  __syncthreads();

  int wv   = threadIdx.x >> 6;  // wave in block: 0..3
  int lane = threadIdx.x & 63;
  int p    = lane >> 4;         // pixel cluster 0..3
  int cl   = lane & 15;         // channel-lane: owns channels cl*16..cl*16+15
  int lpx  = wv * 4 + p;        // local pixel 0..15
  int pix  = P0 + lpx;
  int w = pix % kW, h = pix / kW;

  half8_t lA = *(const half8_t*)&ldsL[lpx][cl * 16];
  half8_t lB = *(const half8_t*)&ldsL[lpx][cl * 16 + 8];

  const float* flowb = flow + (size_t)b * 2 * kHW + pix;
  float bx = (float)w + flowb[0];
  float by = (float)h + flowb[kHW];
  const float* extb = extra + (size_t)b * 2 * kK * kHW + pix;
  const _Float16* Rb = right_t + (size_t)b * kPlane + cl * 16;

  float res[kK];
  #pragma unroll
  for (int k = 0; k < kK; ++k) {
    float xx = bx + (float)(k - 4) + extb[(size_t)(2 * k) * kHW];
    float yy = by + extb[(size_t)(2 * k + 1) * kHW];
    float xf = floorf(xx), yf = floorf(yy);
    float fx = xx - xf, fy = yy - yf;
    int ix0 = (int)xf, iy0 = (int)yf;
    int ix1 = ix0 + 1, iy1 = iy0 + 1;
    bool vx0 = (ix0 >= 0) && (ix0 < kW);
    bool vx1 = (ix1 >= 0) && (ix1 < kW);
    bool vy0 = (iy0 >= 0) && (iy0 < kH);
    bool vy1 = (iy1 >= 0) && (iy1 < kH);
    int xc0 = min(max(ix0, 0), kW - 1);
    int xc1 = min(max(ix1, 0), kW - 1);
    int yc0 = min(max(iy0, 0), kH - 1);
    int yc1 = min(max(iy1, 0), kH - 1);
    float wx0 = 1.f - fx, wy0 = 1.f - fy;
    float w00 = wx0 * wy0 * ((vx0 && vy0) ? 1.f : 0.f);
    float w01 = fx  * wy0 * ((vx1 && vy0) ? 1.f : 0.f);
    float w10 = wx0 * fy  * ((vx0 && vy1) ? 1.f : 0.f);
    float w11 = fx  * fy  * ((vx1 && vy1) ? 1.f : 0.f);

    const _Float16* R00 = Rb + (size_t)(yc0 * kW + xc0) * kC;
    const _Float16* R01 = Rb + (size_t)(yc0 * kW + xc1) * kC;
    const _Float16* R10 = Rb + (size_t)(yc1 * kW + xc0) * kC;
    const _Float16* R11 = Rb + (size_t)(yc1 * kW + xc1) * kC;
    half8_t a00 = *(const half8_t*)(R00), b00 = *(const half8_t*)(R00 + 8);
    half8_t a01 = *(const half8_t*)(R01), b01 = *(const half8_t*)(R01 + 8);
    half8_t a10 = *(const half8_t*)(R10), b10 = *(const half8_t*)(R10 + 8);
    half8_t a11 = *(const half8_t*)(R11), b11 = *(const half8_t*)(R11 + 8);

    float d00 = dot8(b00, lB, dot8(a00, lA, 0.f));
    float d01 = dot8(b01, lB, dot8(a01, lA, 0.f));
    float d10 = dot8(b10, lB, dot8(a10, lA, 0.f));
    float d11 = dot8(b11, lB, dot8(a11, lA, 0.f));
    res[k] = w00 * d00 + w01 * d01 + w10 * d10 + w11 * d11;
  }

  // group = 4 adjacent channel-lanes (64 ch)
  int g = cl >> 2;
  #pragma unroll
  for (int k = 0; k < kK; ++k) {
    float r = res[k];
    r += __shfl_xor(r, 1);
    r += __shfl_xor(r, 2);
    if ((cl & 3) == 0)
      out[((size_t)(b * kG + g) * kK + k) * kHW + pix] = r * (1.f / kGC);
  }
}

// ---- fallback (round-2 kernel) if workspace too small ----
__global__ __launch_bounds__(256) void crestereo_corr_fallback(
    const float* __restrict__ left, const float* __restrict__ right,
    const float* __restrict__ flow, const float* __restrict__ extra,
    float* __restrict__ out)
{
  int t = blockIdx.x * blockDim.x + threadIdx.x;
  int w = t % kW;
  int h = (t / kW) % kH;
  int k = (t / kHW) % kK;
  int g = (t / (kHW * kK)) % kG;
  int b = t / (kHW * kK * kG);

  int pix = h * kW + w;
  const float* flowb = flow + b * 2 * kHW + pix;
  float x = (float)(w + (k - 4)) + flowb[0];
  float y = (float)h + flowb[kHW];
  const float* extb = extra + (size_t)(b * 2 * kK + 2 * k) * kHW + pix;
  x += extb[0];
  y += extb[kHW];

  float xf = floorf(x), yf = floorf(y);
  float fx = x - xf, fy = y - yf;
  int ix0 = (int)xf, iy0 = (int)yf;
  int ix1 = ix0 + 1, iy1 = iy0 + 1;
  bool vx0 = (ix0 >= 0) && (ix0 < kW);
  bool vx1 = (ix1 >= 0) && (ix1 < kW);
  bool vy0 = (iy0 >= 0) && (iy0 < kH);
  bool vy1 = (iy1 >= 0) && (iy1 < kH);
  int xc0 = min(max(ix0, 0), kW - 1);
  int xc1 = min(max(ix1, 0), kW - 1);
  int yc0 = min(max(iy0, 0), kH - 1);
  int yc1 = min(max(iy1, 0), kH - 1);
  float wx0 = 1.f - fx, wy0 = 1.f - fy;
  float w00 = wx0 * wy0 * ((vx0 && vy0) ? 1.f : 0.f);
  float w01 = fx  * wy0 * ((vx1 && vy0) ? 1.f : 0.f);
  float w10 = wx0 * fy  * ((vx0 && vy1) ? 1.f : 0.f);
  float w11 = fx  * fy  * ((vx1 && vy1) ? 1.f : 0.f);
  int idx = yc0 * kW + xc0;
  int dx  = xc1 - xc0;
  int dyw = (yc1 - yc0) * kW;

  const float* Rb = right + (size_t)(b * kC + g * kGC) * kHW + idx;
  const float* Lb = left  + (size_t)(b * kC + g * kGC) * kHW + pix;

  float acc = 0.f;
  #pragma unroll 4
  for (int c = 0; c < kGC; ++c) {
    const float* Rc = Rb + (size_t)c * kHW;
    float l   = Lb[(size_t)c * kHW];
    acc += l * (w00 * Rc[0] + w01 * Rc[dx] + w10 * Rc[dyw] + w11 * Rc[dx + dyw]);
  }
  out[(size_t)((b * kG + g) * kK + k) * kHW + pix] = acc * (1.f / kGC);
}

extern "C" void kernel_launch(void* const* d_in, const int* in_sizes, int n_in,
                              void* d_out, int out_size, void* d_ws, size_t ws_size,
                              hipStream_t stream) {
  const float* left  = (const float*)d_in[0];
  const float* right = (const float*)d_in[1];
  const float* flow  = (const float*)d_in[2];
  const float* extra = (const float*)d_in[3];
  float* out = (float*)d_out;

  size_t need = (size_t)kB * kPlane * sizeof(_Float16);  // ~18.9 MB (right_t)
  if (ws_size >= need) {
    _Float16* right_t = (_Float16*)d_ws;
    dim3 tgrid(kHW / 64, kC / 64, kB);       // 288 x 4 x 2
    transpose_right_fp16<<<tgrid, 256, 0, stream>>>(right, right_t);
    int blocks = kB * kBlocksPerBatch;       // 2304 blocks, 16 px each
    corr_fp16_kernel<<<blocks, 256, 0, stream>>>(left, right_t, flow, extra, out);
  } else {
    int total = kB * kG * kK * kH * kW;
    crestereo_corr_fallback<<<(total + 255) / 256, 256, 0, stream>>>(
        left, right, flow, extra, out);
  }
}

// Round 8
// 152.956 us; speedup vs baseline: 2.1419x; 2.1419x over previous
//
#include <hip/hip_runtime.h>

// CREStereo grouped correlation, round 8.
// R7 post-mortem: launch_bounds(256,3) on the R6 kernel made the allocator
// SPILL (VGPR 172->84, WRITE_SIZE 5->454 MB, main 62->230us). Reverted.
// R8 changes exactly one thing vs R6: wave layout 4px x 16 lanes x 16ch ->
// 2px x 32 lanes x 8ch. One half8 (16B dwordx4) per tap instead of two ->
// tap liveness per k halves (16 VGPRs vs 32), group-reduce moved inside the
// k-loop (single live accumulator). Goal: VGPR <=128 NATURALLY -> 4 waves/SIMD
// (2x R6 residency) for this latency-bound kernel.
// Pre-pass: R6's known-good both-tensor f32->fp16 transpose.

namespace {
constexpr int kB = 2;
constexpr int kC = 256;
constexpr int kH = 96;
constexpr int kW = 192;
constexpr int kG = 4;
constexpr int kGC = kC / kG;              // 64
constexpr int kK = 9;
constexpr int kHW = kH * kW;              // 18432
constexpr size_t kPlane = (size_t)kC * kHW;
}

typedef _Float16 half8_t __attribute__((ext_vector_type(8)));
typedef _Float16 half4_t __attribute__((ext_vector_type(4)));
typedef _Float16 half2_t __attribute__((ext_vector_type(2)));

__device__ __forceinline__ float dot8(half8_t a, half8_t b, float acc) {
#if __has_builtin(__builtin_amdgcn_fdot2)
  #pragma unroll
  for (int i = 0; i < 4; ++i) {
    half2_t a2 = {a[2 * i], a[2 * i + 1]};
    half2_t b2 = {b[2 * i], b[2 * i + 1]};
    acc = __builtin_amdgcn_fdot2(a2, b2, acc, false);
  }
#else
  #pragma unroll
  for (int i = 0; i < 8; ++i) acc += (float)a[i] * (float)b[i];
#endif
  return acc;
}

// ---- transpose [C][HW] f32 -> [HW][C] fp16, both tensors (z = b*2+tensor) ----
__global__ __launch_bounds__(256) void transpose_fp16(
    const float* __restrict__ left, const float* __restrict__ right,
    _Float16* __restrict__ left_t, _Float16* __restrict__ right_t)
{
  __shared__ float tile[64][65];
  int pt = blockIdx.x;          // pixel tile 0..287
  int ct = blockIdx.y;          // channel tile 0..3
  int z  = blockIdx.z;
  int b  = z >> 1;
  const float* in = (z & 1) ? right : left;
  _Float16*   dst = (z & 1) ? right_t : left_t;
  int p0 = pt * 64, c0 = ct * 64;
  const float* inb = in + (size_t)b * kPlane;
  _Float16*   outb = dst + (size_t)b * kPlane;
  int t = threadIdx.x;
  int cl = t >> 2;              // channel within tile
  int q  = t & 3;
  #pragma unroll
  for (int i = 0; i < 4; ++i) {
    int j = q + 4 * i;          // float4 index along pixels
    float4 v = *(const float4*)(inb + (size_t)(c0 + cl) * kHW + p0 + 4 * j);
    tile[cl][4 * j + 0] = v.x;
    tile[cl][4 * j + 1] = v.y;
    tile[cl][4 * j + 2] = v.z;
    tile[cl][4 * j + 3] = v.w;
  }
  __syncthreads();
  int pl = t >> 2;              // pixel within tile
  #pragma unroll
  for (int i = 0; i < 4; ++i) {
    int c4 = (t & 3) + 4 * i;   // half4 index along channels
    half4_t hv;
    hv[0] = (_Float16)tile[4 * c4 + 0][pl];
    hv[1] = (_Float16)tile[4 * c4 + 1][pl];
    hv[2] = (_Float16)tile[4 * c4 + 2][pl];
    hv[3] = (_Float16)tile[4 * c4 + 3][pl];
    *(half4_t*)(outb + (size_t)(p0 + pl) * kC + c0 + 4 * c4) = hv;
  }
}

// ---- main: wave = 2 pixels x 32 lanes; lane owns 8 channels (one half8) ----
__global__ __launch_bounds__(256) void corr_fp16_kernel(
    const _Float16* __restrict__ left_t, const _Float16* __restrict__ right_t,
    const float* __restrict__ flow, const float* __restrict__ extra,
    float* __restrict__ out)
{
  int gw   = blockIdx.x * 4 + (threadIdx.x >> 6);  // global wave id
  int lane = threadIdx.x & 63;
  int base = gw * 2;            // first of 2 pixels (global, b-major)
  int b    = base / kHW;        // kHW even: no wave straddles b
  int pl0  = base % kHW;
  int p    = lane >> 5;         // pixel cluster 0..1
  int cl   = lane & 31;         // channel-lane: owns channels cl*8..cl*8+7
  int pix  = pl0 + p;
  int w = pix % kW, h = pix / kW;

  half8_t l8 = *(const half8_t*)(left_t + ((size_t)b * kHW + pix) * kC + cl * 8);

  const float* flowb = flow + (size_t)b * 2 * kHW + pix;
  float bx = (float)w + flowb[0];
  float by = (float)h + flowb[kHW];
  const float* extb = extra + (size_t)b * 2 * kK * kHW + pix;
  const _Float16* Rb = right_t + (size_t)b * kPlane + cl * 8;

  int g = cl >> 3;              // group 0..3 (8 lanes x 8 ch = 64 ch)
  float* outp = out + (size_t)b * kG * kK * kHW + pix;

  #pragma unroll
  for (int k = 0; k < kK; ++k) {
    float xx = bx + (float)(k - 4) + extb[(size_t)(2 * k) * kHW];
    float yy = by + extb[(size_t)(2 * k + 1) * kHW];
    float xf = floorf(xx), yf = floorf(yy);
    float fx = xx - xf, fy = yy - yf;
    int ix0 = (int)xf, iy0 = (int)yf;
    int ix1 = ix0 + 1, iy1 = iy0 + 1;
    bool vx0 = (ix0 >= 0) && (ix0 < kW);
    bool vx1 = (ix1 >= 0) && (ix1 < kW);
    bool vy0 = (iy0 >= 0) && (iy0 < kH);
    bool vy1 = (iy1 >= 0) && (iy1 < kH);
    int xc0 = min(max(ix0, 0), kW - 1);
    int xc1 = min(max(ix1, 0), kW - 1);
    int yc0 = min(max(iy0, 0), kH - 1);
    int yc1 = min(max(iy1, 0), kH - 1);
    float wx0 = 1.f - fx, wy0 = 1.f - fy;
    float w00 = wx0 * wy0 * ((vx0 && vy0) ? 1.f : 0.f);
    float w01 = fx  * wy0 * ((vx1 && vy0) ? 1.f : 0.f);
    float w10 = wx0 * fy  * ((vx0 && vy1) ? 1.f : 0.f);
    float w11 = fx  * fy  * ((vx1 && vy1) ? 1.f : 0.f);

    half8_t t00 = *(const half8_t*)(Rb + (size_t)(yc0 * kW + xc0) * kC);
    half8_t t01 = *(const half8_t*)(Rb + (size_t)(yc0 * kW + xc1) * kC);
    half8_t t10 = *(const half8_t*)(Rb + (size_t)(yc1 * kW + xc0) * kC);
    half8_t t11 = *(const half8_t*)(Rb + (size_t)(yc1 * kW + xc1) * kC);

    float d00 = dot8(t00, l8, 0.f);
    float d01 = dot8(t01, l8, 0.f);
    float d10 = dot8(t10, l8, 0.f);
    float d11 = dot8(t11, l8, 0.f);
    float r = w00 * d00 + w01 * d01 + w10 * d10 + w11 * d11;

    // reduce 8 channel-lanes -> group sum; store immediately (1 live acc)
    r += __shfl_xor(r, 1);
    r += __shfl_xor(r, 2);
    r += __shfl_xor(r, 4);
    if ((cl & 7) == 0)
      outp[((size_t)g * kK + k) * kHW] = r * (1.f / kGC);
  }
}

// ---- fallback (round-2 kernel) if workspace too small ----
__global__ __launch_bounds__(256) void crestereo_corr_fallback(
    const float* __restrict__ left, const float* __restrict__ right,
    const float* __restrict__ flow, const float* __restrict__ extra,
    float* __restrict__ out)
{
  int t = blockIdx.x * blockDim.x + threadIdx.x;
  int w = t % kW;
  int h = (t / kW) % kH;
  int k = (t / kHW) % kK;
  int g = (t / (kHW * kK)) % kG;
  int b = t / (kHW * kK * kG);

  int pix = h * kW + w;
  const float* flowb = flow + b * 2 * kHW + pix;
  float x = (float)(w + (k - 4)) + flowb[0];
  float y = (float)h + flowb[kHW];
  const float* extb = extra + (size_t)(b * 2 * kK + 2 * k) * kHW + pix;
  x += extb[0];
  y += extb[kHW];

  float xf = floorf(x), yf = floorf(y);
  float fx = x - xf, fy = y - yf;
  int ix0 = (int)xf, iy0 = (int)yf;
  int ix1 = ix0 + 1, iy1 = iy0 + 1;
  bool vx0 = (ix0 >= 0) && (ix0 < kW);
  bool vx1 = (ix1 >= 0) && (ix1 < kW);
  bool vy0 = (iy0 >= 0) && (iy0 < kH);
  bool vy1 = (iy1 >= 0) && (iy1 < kH);
  int xc0 = min(max(ix0, 0), kW - 1);
  int xc1 = min(max(ix1, 0), kW - 1);
  int yc0 = min(max(iy0, 0), kH - 1);
  int yc1 = min(max(iy1, 0), kH - 1);
  float wx0 = 1.f - fx, wy0 = 1.f - fy;
  float w00 = wx0 * wy0 * ((vx0 && vy0) ? 1.f : 0.f);
  float w01 = fx  * wy0 * ((vx1 && vy0) ? 1.f : 0.f);
  float w10 = wx0 * fy  * ((vx0 && vy1) ? 1.f : 0.f);
  float w11 = fx  * fy  * ((vx1 && vy1) ? 1.f : 0.f);
  int idx = yc0 * kW + xc0;
  int dx  = xc1 - xc0;
  int dyw = (yc1 - yc0) * kW;

  const float* Rb = right + (size_t)(b * kC + g * kGC) * kHW + idx;
  const float* Lb = left  + (size_t)(b * kC + g * kGC) * kHW + pix;

  float acc = 0.f;
  #pragma unroll 4
  for (int c = 0; c < kGC; ++c) {
    const float* Rc = Rb + (size_t)c * kHW;
    float l   = Lb[(size_t)c * kHW];
    acc += l * (w00 * Rc[0] + w01 * Rc[dx] + w10 * Rc[dyw] + w11 * Rc[dx + dyw]);
  }
  out[(size_t)((b * kG + g) * kK + k) * kHW + pix] = acc * (1.f / kGC);
}

extern "C" void kernel_launch(void* const* d_in, const int* in_sizes, int n_in,
                              void* d_out, int out_size, void* d_ws, size_t ws_size,
                              hipStream_t stream) {
  const float* left  = (const float*)d_in[0];
  const float* right = (const float*)d_in[1];
  const float* flow  = (const float*)d_in[2];
  const float* extra = (const float*)d_in[3];
  float* out = (float*)d_out;

  size_t need = 2 * (size_t)kB * kPlane * sizeof(_Float16);  // ~37.7 MB
  if (ws_size >= need) {
    _Float16* left_t  = (_Float16*)d_ws;
    _Float16* right_t = left_t + (size_t)kB * kPlane;
    dim3 tgrid(kHW / 64, kC / 64, kB * 2);   // 288 x 4 x 4
    transpose_fp16<<<tgrid, 256, 0, stream>>>(left, right, left_t, right_t);
    int waves = kB * kHW / 2;                // 18432 waves, 2 px each
    corr_fp16_kernel<<<waves / 4, 256, 0, stream>>>(left_t, right_t, flow, extra, out);
  } else {
    int total = kB * kG * kK * kH * kW;
    crestereo_corr_fallback<<<(total + 255) / 256, 256, 0, stream>>>(
        left, right, flow, extra, out);
  }
}